// Round 7
// baseline (168.017 us; speedup 1.0000x reference)
//
#include <hip/hip_runtime.h>
#include <hip/hip_bf16.h>
#include <math.h>

#define NTOK 512      // N
#define BATCH 2
#define HID 256
#define HEADS 4
#define HD 64
#define NEG_INF -1e9f

typedef short bf16x8 __attribute__((ext_vector_type(8)));
typedef short bf16x4 __attribute__((ext_vector_type(4)));
typedef float f32x4 __attribute__((ext_vector_type(4)));
typedef float f32x2 __attribute__((ext_vector_type(2)));

__device__ __forceinline__ short f2bf(float f) {
    union { __hip_bfloat16 h; short s; } u;
    u.h = __float2bfloat16(f);
    return u.s;
}

// ---------------------------------------------------------------------------
// Stage A: fused 5-way projection GEMM.  Y = X @ W (+bias)
// ---------------------------------------------------------------------------
__global__ __launch_bounds__(256) void pga_proj5(
    const float* __restrict__ x,
    const float* __restrict__ Wq, const float* __restrict__ bq,
    const float* __restrict__ Wk, const float* __restrict__ bk,
    const float* __restrict__ Wv, const float* __restrict__ bv,
    const float* __restrict__ Wp1, const float* __restrict__ bp1,
    float* __restrict__ Q, float* __restrict__ K, float* __restrict__ V,
    float* __restrict__ A, float* __restrict__ BbT)
{
    __shared__ float xs[16][HID];
    const int m0 = blockIdx.x * 16;
    const int which = blockIdx.y;
    const int t = threadIdx.x;
    const int cg = t & 63;
    const int rg = t >> 6;

    {
        const float4* xg = (const float4*)(x + m0 * HID);
        float4* xsv = (float4*)xs;
        #pragma unroll
        for (int k = 0; k < 4; ++k) xsv[t + 256 * k] = xg[t + 256 * k];
    }
    __syncthreads();

    const float* W; const float* bvec; float* out; bool transposed = false;
    switch (which) {
        case 0: W = Wq; bvec = bq; out = Q; break;
        case 1: W = Wk; bvec = bk; out = K; break;
        case 2: W = Wv; bvec = bv; out = V; break;
        case 3: W = Wp1; bvec = bp1; out = A; break;
        default: W = Wp1 + HID * HID; bvec = nullptr; out = BbT; transposed = true; break;
    }

    float4 bias4 = make_float4(0.f, 0.f, 0.f, 0.f);
    if (bvec) bias4 = ((const float4*)bvec)[cg];
    float4 acc[4] = {bias4, bias4, bias4, bias4};

    const float4* W4 = (const float4*)W;
    for (int kq = 0; kq < 64; ++kq) {
        const float4 w0 = W4[(4 * kq + 0) * 64 + cg];
        const float4 w1 = W4[(4 * kq + 1) * 64 + cg];
        const float4 w2 = W4[(4 * kq + 2) * 64 + cg];
        const float4 w3 = W4[(4 * kq + 3) * 64 + cg];
        #pragma unroll
        for (int r = 0; r < 4; ++r) {
            const float4 xv = ((const float4*)xs[4 * rg + r])[kq];
            acc[r].x = fmaf(xv.x, w0.x, fmaf(xv.y, w1.x, fmaf(xv.z, w2.x, fmaf(xv.w, w3.x, acc[r].x))));
            acc[r].y = fmaf(xv.x, w0.y, fmaf(xv.y, w1.y, fmaf(xv.z, w2.y, fmaf(xv.w, w3.y, acc[r].y))));
            acc[r].z = fmaf(xv.x, w0.z, fmaf(xv.y, w1.z, fmaf(xv.z, w2.z, fmaf(xv.w, w3.z, acc[r].z))));
            acc[r].w = fmaf(xv.x, w0.w, fmaf(xv.y, w1.w, fmaf(xv.z, w2.w, fmaf(xv.w, w3.w, acc[r].w))));
        }
    }

    if (!transposed) {
        #pragma unroll
        for (int r = 0; r < 4; ++r)
            ((float4*)(out + (m0 + 4 * rg + r) * HID))[cg] = acc[r];
    } else {
        const int b = m0 >= NTOK;
        const int n0 = m0 - b * NTOK;
        #pragma unroll
        for (int r = 0; r < 4; ++r) {
            const int row = n0 + 4 * rg + r;
            float* ob = BbT + b * (HID * NTOK);
            ob[(4 * cg + 0) * NTOK + row] = acc[r].x;
            ob[(4 * cg + 1) * NTOK + row] = acc[r].y;
            ob[(4 * cg + 2) * NTOK + row] = acc[r].z;
            ob[(4 * cg + 3) * NTOK + row] = acc[r].w;
        }
    }
}

// ---------------------------------------------------------------------------
// Stage B: physics bias, DENSE + PACKED-F32. One block per (b,i) row, 512
//   threads, thread t owns column j=t: all bb loads coalesced (4 lines/wave
//   -- kills the sparse variant's ~16-32 line TA gather that pinned it at
//   47-50us). The 2x VALU cost of dense is halved back via v_pk_*_f32:
//   d-loop processes d,d+1 as f32x2 and head-pairs (h0,h1)/(h2,h3) as f32x2.
//   arow/wp2 are wave-uniform global reads -> scalar pipe (R6: SGPR 80).
//   No LDS at all. Mask folded into output via select (no prefill).
// ---------------------------------------------------------------------------
__global__ __launch_bounds__(512) void pga_bias(
    const float* __restrict__ A, const float* __restrict__ BbT,
    const float* __restrict__ Wp2, const float* __restrict__ bp2,
    const int* __restrict__ adj, float* __restrict__ biasg)
{
    const int t = threadIdx.x;          // 0..511 = j
    const int b = blockIdx.x >> 9;
    const int i = blockIdx.x & 511;

    const int valid = adj[i * NTOK + t];
    const float* bb = BbT + b * (HID * NTOK) + t;              // column j=t
    const float* arow = A + ((size_t)(b * NTOK) + i) * HID;    // uniform
    const f32x2* arow2 = (const f32x2*)arow;
    const float4* wp4 = (const float4*)Wp2;                    // uniform

    f32x2 a01 = {0.f, 0.f}, a23 = {0.f, 0.f};  // packed head accums
    #pragma unroll 8
    for (int d2 = 0; d2 < HID / 2; ++d2) {
        const int d = d2 * 2;
        const f32x2 av = arow2[d2];                 // uniform (scalar pipe)
        f32x2 x;
        x[0] = av[0] + bb[d * NTOK];
        x[1] = av[1] + bb[(d + 1) * NTOK];
        const f32x2 x2 = x * x;
        const f32x2 u2 = x * (x2 * 0.10293919f + 2.3021176f);
        f32x2 r;
        r[0] = __builtin_amdgcn_rcpf(__builtin_amdgcn_exp2f(u2[0]) + 1.0f);
        r[1] = __builtin_amdgcn_rcpf(__builtin_amdgcn_exp2f(u2[1]) + 1.0f);
        const f32x2 g = x - x * r;                  // gelu(x0), gelu(x1)
        const float4 wa = wp4[d];
        const float4 wb = wp4[d + 1];
        const f32x2 g0 = {g[0], g[0]};
        const f32x2 g1 = {g[1], g[1]};
        a01 += g0 * (f32x2){wa.x, wa.y};
        a01 += g1 * (f32x2){wb.x, wb.y};
        a23 += g0 * (f32x2){wa.z, wa.w};
        a23 += g1 * (f32x2){wb.z, wb.w};
    }

    const float4 bp = *(const float4*)bp2;
    float* o = biasg + (((size_t)b * HEADS) * NTOK + i) * NTOK + t;
    o[0 * NTOK * NTOK] = (valid > 0) ? a01[0] + bp.x : NEG_INF;
    o[1 * NTOK * NTOK] = (valid > 0) ? a01[1] + bp.y : NEG_INF;
    o[2 * NTOK * NTOK] = (valid > 0) ? a23[0] + bp.z : NEG_INF;
    o[3 * NTOK * NTOK] = (valid > 0) ? a23[1] + bp.w : NEG_INF;
}

// ---------------------------------------------------------------------------
// Stage C: MFMA attention, flash-decoding j-split. grid = 256 blocks =
//   (b, h, qt, js). biasg carries the mask (NEG_INF for invalid), so no
//   adj reads. Bias loads are issued FIRST (32 independent loads) and
//   consumed after QK^T -> HBM/L2 latency hides under staging + MFMA.
// ---------------------------------------------------------------------------
#define KT_STRIDE 72
#define VN_STRIDE 76
#define PL_STRIDE 136

__global__ __launch_bounds__(256) void pga_attn(
    const float* __restrict__ Q, const float* __restrict__ K,
    const float* __restrict__ V, const float* __restrict__ biasg,
    float* __restrict__ op0, float* __restrict__ op1,
    float* __restrict__ op2, float* __restrict__ op3,
    float* __restrict__ mlbuf)
{
    __shared__ short Kt[128 * KT_STRIDE];
    __shared__ short Vn[128 * VN_STRIDE];
    __shared__ short Pl[4][16 * PL_STRIDE];

    const int blk = blockIdx.x;
    const int js = blk & 3;
    const int qt = (blk >> 2) & 7;
    const int h  = (blk >> 5) & 3;
    const int b  = blk >> 7;
    const int t = threadIdx.x;
    const int w = t >> 6;
    const int lane = t & 63;
    const int ln15 = lane & 15;
    const int quad = lane >> 4;

    float* Opart = (js == 0) ? op0 : (js == 1) ? op1 : (js == 2) ? op2 : op3;
    const int j0 = js * 128;
    const int i0w = qt * 64 + w * 16;

    // ---- issue bias loads FIRST (independent; consumed after QK^T) ----
    float bpre[8][4];
    {
        const float* bgb = biasg + ((size_t)(b * HEADS + h)) * NTOK * NTOK;
        #pragma unroll
        for (int nt = 0; nt < 8; ++nt) {
            const int j = j0 + nt * 16 + ln15;
            #pragma unroll
            for (int r = 0; r < 4; ++r)
                bpre[nt][r] = bgb[(size_t)(i0w + quad * 4 + r) * NTOK + j];
        }
    }

    // ---- Q A-fragments (scale folded into bf16 conversion), float4 loads ----
    bf16x8 aq0, aq1;
    {
        const float* qrow = Q + ((size_t)(b * NTOK) + i0w + ln15) * HID + h * HD;
        const float4 q0 = ((const float4*)qrow)[quad * 2];
        const float4 q1 = ((const float4*)qrow)[quad * 2 + 1];
        const float4 q2 = ((const float4*)qrow)[8 + quad * 2];
        const float4 q3 = ((const float4*)qrow)[8 + quad * 2 + 1];
        aq0[0] = f2bf(q0.x * 0.125f); aq0[1] = f2bf(q0.y * 0.125f);
        aq0[2] = f2bf(q0.z * 0.125f); aq0[3] = f2bf(q0.w * 0.125f);
        aq0[4] = f2bf(q1.x * 0.125f); aq0[5] = f2bf(q1.y * 0.125f);
        aq0[6] = f2bf(q1.z * 0.125f); aq0[7] = f2bf(q1.w * 0.125f);
        aq1[0] = f2bf(q2.x * 0.125f); aq1[1] = f2bf(q2.y * 0.125f);
        aq1[2] = f2bf(q2.z * 0.125f); aq1[3] = f2bf(q2.w * 0.125f);
        aq1[4] = f2bf(q3.x * 0.125f); aq1[5] = f2bf(q3.y * 0.125f);
        aq1[6] = f2bf(q3.z * 0.125f); aq1[7] = f2bf(q3.w * 0.125f);
    }

    // ---- stage K,V tile ----
    for (int k = 0; k < 8; ++k) {
        const int flat4 = k * 256 + t;
        const int jl = flat4 >> 4, dq = flat4 & 15;
        const float4 kv = ((const float4*)(K + ((size_t)(b * NTOK) + j0 + jl) * HID + h * HD))[dq];
        const float4 vv = ((const float4*)(V + ((size_t)(b * NTOK) + j0 + jl) * HID + h * HD))[dq];
        bf16x4 ks, vs;
        ks[0] = f2bf(kv.x); ks[1] = f2bf(kv.y); ks[2] = f2bf(kv.z); ks[3] = f2bf(kv.w);
        vs[0] = f2bf(vv.x); vs[1] = f2bf(vv.y); vs[2] = f2bf(vv.z); vs[3] = f2bf(vv.w);
        *(bf16x4*)&Kt[jl * KT_STRIDE + dq * 4] = ks;
        *(bf16x4*)&Vn[jl * VN_STRIDE + dq * 4] = vs;
    }
    __syncthreads();

    // ---- S = Q K^T ----
    f32x4 s[8];
    #pragma unroll
    for (int nt = 0; nt < 8; ++nt) {
        const int krow = nt * 16 + ln15;
        const bf16x8 bk0 = *(const bf16x8*)&Kt[krow * KT_STRIDE + quad * 8];
        const bf16x8 bk1 = *(const bf16x8*)&Kt[krow * KT_STRIDE + 32 + quad * 8];
        f32x4 acc = (f32x4){0.f, 0.f, 0.f, 0.f};
        acc = __builtin_amdgcn_mfma_f32_16x16x32_bf16(aq0, bk0, acc, 0, 0, 0);
        acc = __builtin_amdgcn_mfma_f32_16x16x32_bf16(aq1, bk1, acc, 0, 0, 0);
        s[nt] = acc;
    }

    // ---- add masked bias (mask already folded into biasg) ----
    #pragma unroll
    for (int nt = 0; nt < 8; ++nt)
        #pragma unroll
        for (int r = 0; r < 4; ++r)
            s[nt][r] += bpre[nt][r];

    // ---- single-tile softmax stats ----
    float p[8][4], m_r[4], l_r[4];
    #pragma unroll
    for (int r = 0; r < 4; ++r) {
        float mx = s[0][r];
        #pragma unroll
        for (int nt = 1; nt < 8; ++nt) mx = fmaxf(mx, s[nt][r]);
        #pragma unroll
        for (int off = 1; off < 16; off <<= 1) mx = fmaxf(mx, __shfl_xor(mx, off, 64));
        float rs = 0.f;
        #pragma unroll
        for (int nt = 0; nt < 8; ++nt) { p[nt][r] = __expf(s[nt][r] - mx); rs += p[nt][r]; }
        #pragma unroll
        for (int off = 1; off < 16; off <<= 1) rs += __shfl_xor(rs, off, 64);
        m_r[r] = mx; l_r[r] = rs;
    }

    // ---- P -> per-wave LDS (C-layout scatter), read back as A-frags ----
    #pragma unroll
    for (int nt = 0; nt < 8; ++nt)
        #pragma unroll
        for (int r = 0; r < 4; ++r)
            Pl[w][(quad * 4 + r) * PL_STRIDE + nt * 16 + ln15] = f2bf(p[nt][r]);

    bf16x8 ap[4];
    #pragma unroll
    for (int kt = 0; kt < 4; ++kt)
        ap[kt] = *(const bf16x8*)&Pl[w][ln15 * PL_STRIDE + kt * 32 + quad * 8];

    // ---- O_partial = P V (unnormalized) ----
    f32x4 o_acc[4];
    #pragma unroll
    for (int dt = 0; dt < 4; ++dt) o_acc[dt] = (f32x4){0.f, 0.f, 0.f, 0.f};
    #pragma unroll
    for (int dt = 0; dt < 4; ++dt) {
        #pragma unroll
        for (int kt = 0; kt < 4; ++kt) {
            bf16x8 bv;
            #pragma unroll
            for (int jj = 0; jj < 8; ++jj)
                bv[jj] = Vn[(kt * 32 + quad * 8 + jj) * VN_STRIDE + dt * 16 + ln15];
            o_acc[dt] = __builtin_amdgcn_mfma_f32_16x16x32_bf16(ap[kt], bv, o_acc[dt], 0, 0, 0);
        }
    }

    // ---- write partials ----
    #pragma unroll
    for (int dt = 0; dt < 4; ++dt)
        #pragma unroll
        for (int r = 0; r < 4; ++r) {
            const int i = i0w + quad * 4 + r;
            Opart[((size_t)(b * NTOK) + i) * HID + h * HD + dt * 16 + ln15] = o_acc[dt][r];
        }
    if (ln15 == 0) {
        #pragma unroll
        for (int r = 0; r < 4; ++r) {
            const int i = i0w + quad * 4 + r;
            float* mlp = mlbuf + (((size_t)(js * BATCH + b) * NTOK + i) * HEADS + h) * 2;
            mlp[0] = m_r[r]; mlp[1] = l_r[r];
        }
    }
}

// ---------------------------------------------------------------------------
// Stage D: merge attention partials + out = O@Wo + bo.
// ---------------------------------------------------------------------------
__global__ __launch_bounds__(256) void pga_outproj(
    const float* __restrict__ op0, const float* __restrict__ op1,
    const float* __restrict__ op2, const float* __restrict__ op3,
    const float* __restrict__ mlbuf,
    const float* __restrict__ Wo, const float* __restrict__ bo,
    float* __restrict__ out)
{
    __shared__ float xs[4][HID];
    const int m0 = blockIdx.x * 4;
    const int t = threadIdx.x;
    const int c = t;                  // col for merge phase
    const int h = c >> 6;

    const float* ops[4] = {op0, op1, op2, op3};

    #pragma unroll
    for (int r = 0; r < 4; ++r) {
        const int ig = m0 + r;
        const int b = ig >> 9, i = ig & 511;
        float po[4], ms[4], ls[4];
        #pragma unroll
        for (int s = 0; s < 4; ++s) {
            po[s] = ops[s][(size_t)ig * HID + c];
            const float* mlp = mlbuf + (((size_t)(s * BATCH + b) * NTOK + i) * HEADS + h) * 2;
            ms[s] = mlp[0]; ls[s] = mlp[1];
        }
        const float mmax = fmaxf(fmaxf(ms[0], ms[1]), fmaxf(ms[2], ms[3]));
        float L = 0.f, val = 0.f;
        #pragma unroll
        for (int s = 0; s < 4; ++s) {
            const float e = __expf(ms[s] - mmax);
            L += ls[s] * e;
            val = fmaf(po[s], e, val);
        }
        xs[r][c] = val / L;
    }
    __syncthreads();

    const int cg = t & 63;
    const int rg = t >> 6;            // each thread: 1 row x 4 cols
    float4 acc = ((const float4*)bo)[cg];

    const float4* W4 = (const float4*)Wo;
    const float4* xrow = (const float4*)xs[rg];
    #pragma unroll 2
    for (int kq = 0; kq < 64; ++kq) {
        const float4 w0 = W4[(4 * kq + 0) * 64 + cg];
        const float4 w1 = W4[(4 * kq + 1) * 64 + cg];
        const float4 w2 = W4[(4 * kq + 2) * 64 + cg];
        const float4 w3 = W4[(4 * kq + 3) * 64 + cg];
        const float4 xv = xrow[kq];
        acc.x = fmaf(xv.x, w0.x, fmaf(xv.y, w1.x, fmaf(xv.z, w2.x, fmaf(xv.w, w3.x, acc.x))));
        acc.y = fmaf(xv.x, w0.y, fmaf(xv.y, w1.y, fmaf(xv.z, w2.y, fmaf(xv.w, w3.y, acc.y))));
        acc.z = fmaf(xv.x, w0.z, fmaf(xv.y, w1.z, fmaf(xv.z, w2.z, fmaf(xv.w, w3.z, acc.z))));
        acc.w = fmaf(xv.x, w0.w, fmaf(xv.y, w1.w, fmaf(xv.z, w2.w, fmaf(xv.w, w3.w, acc.w))));
    }
    ((float4*)(out + (m0 + rg) * HID))[cg] = acc;
}

extern "C" void kernel_launch(void* const* d_in, const int* in_sizes, int n_in,
                              void* d_out, int out_size, void* d_ws, size_t ws_size,
                              hipStream_t stream) {
    const float* x   = (const float*)d_in[0];
    const int*   adj = (const int*)d_in[1];
    const float* Wq  = (const float*)d_in[2];
    const float* bq  = (const float*)d_in[3];
    const float* Wk  = (const float*)d_in[4];
    const float* bk  = (const float*)d_in[5];
    const float* Wv  = (const float*)d_in[6];
    const float* bv  = (const float*)d_in[7];
    const float* Wo  = (const float*)d_in[8];
    const float* bo  = (const float*)d_in[9];
    const float* Wp1 = (const float*)d_in[10];
    const float* bp1 = (const float*)d_in[11];
    const float* Wp2 = (const float*)d_in[12];
    const float* bp2 = (const float*)d_in[13];
    float* out = (float*)d_out;

    // ws layout (floats), ~15.9 MB total. A/BbT die after pga_bias and are
    // reused as Opart[0]/Opart[1] by pga_attn (same-stream ordering).
    float* ws   = (float*)d_ws;
    float* Q    = ws;
    float* K    = ws + 262144;
    float* V    = ws + 2 * 262144;
    float* A    = ws + 3 * 262144;     // -> Opart[0]
    float* BbT  = ws + 4 * 262144;     // -> Opart[1]
    float* bias = ws + 5 * 262144;     // 2097152 floats
    float* Op2  = ws + 5 * 262144 + 2097152;
    float* Op3  = Op2 + 262144;
    float* mlb  = Op3 + 262144;        // 32768 floats

    pga_proj5<<<dim3(64, 5), 256, 0, stream>>>(x, Wq, bq, Wk, bk, Wv, bv,
                                               Wp1, bp1, Q, K, V, A, BbT);
    pga_bias<<<1024, 512, 0, stream>>>(A, BbT, Wp2, bp2, adj, bias);
    pga_attn<<<256, 256, 0, stream>>>(Q, K, V, bias, A, BbT, Op2, Op3, mlb);
    pga_outproj<<<256, 256, 0, stream>>>(A, BbT, Op2, Op3, mlb, Wo, bo, out);
}

// Round 8
// 164.326 us; speedup vs baseline: 1.0225x; 1.0225x over previous
//
#include <hip/hip_runtime.h>
#include <hip/hip_bf16.h>
#include <math.h>

#define NTOK 512      // N
#define BATCH 2
#define HID 256
#define HEADS 4
#define HD 64
#define NEG_INF -1e9f

typedef short bf16x8 __attribute__((ext_vector_type(8)));
typedef short bf16x4 __attribute__((ext_vector_type(4)));
typedef float f32x4 __attribute__((ext_vector_type(4)));

__device__ __forceinline__ short f2bf(float f) {
    union { __hip_bfloat16 h; short s; } u;
    u.h = __float2bfloat16(f);
    return u.s;
}

// tanh-form gelu, exp2+rcp based (5 VALU + 2 trans):
//   gelu(x) = x - x * rcp(exp2(x*(2.3021176 + 0.10293919*x^2)) + 1)
__device__ __forceinline__ float fast_gelu(float x) {
    const float x2 = x * x;
    const float u2 = x * fmaf(x2, 0.10293919f, 2.3021176f);
    const float e = __builtin_amdgcn_exp2f(u2);
    const float r = __builtin_amdgcn_rcpf(e + 1.0f);
    return fmaf(-x, r, x);
}

// ---------------------------------------------------------------------------
// Stage A: fused 5-way projection GEMM.  Y = X @ W (+bias)
// ---------------------------------------------------------------------------
__global__ __launch_bounds__(256) void pga_proj5(
    const float* __restrict__ x,
    const float* __restrict__ Wq, const float* __restrict__ bq,
    const float* __restrict__ Wk, const float* __restrict__ bk,
    const float* __restrict__ Wv, const float* __restrict__ bv,
    const float* __restrict__ Wp1, const float* __restrict__ bp1,
    float* __restrict__ Q, float* __restrict__ K, float* __restrict__ V,
    float* __restrict__ A, float* __restrict__ BbT)
{
    __shared__ float xs[16][HID];
    const int m0 = blockIdx.x * 16;
    const int which = blockIdx.y;
    const int t = threadIdx.x;
    const int cg = t & 63;
    const int rg = t >> 6;

    {
        const float4* xg = (const float4*)(x + m0 * HID);
        float4* xsv = (float4*)xs;
        #pragma unroll
        for (int k = 0; k < 4; ++k) xsv[t + 256 * k] = xg[t + 256 * k];
    }
    __syncthreads();

    const float* W; const float* bvec; float* out; bool transposed = false;
    switch (which) {
        case 0: W = Wq; bvec = bq; out = Q; break;
        case 1: W = Wk; bvec = bk; out = K; break;
        case 2: W = Wv; bvec = bv; out = V; break;
        case 3: W = Wp1; bvec = bp1; out = A; break;
        default: W = Wp1 + HID * HID; bvec = nullptr; out = BbT; transposed = true; break;
    }

    float4 bias4 = make_float4(0.f, 0.f, 0.f, 0.f);
    if (bvec) bias4 = ((const float4*)bvec)[cg];
    float4 acc[4] = {bias4, bias4, bias4, bias4};

    const float4* W4 = (const float4*)W;
    for (int kq = 0; kq < 64; ++kq) {
        const float4 w0 = W4[(4 * kq + 0) * 64 + cg];
        const float4 w1 = W4[(4 * kq + 1) * 64 + cg];
        const float4 w2 = W4[(4 * kq + 2) * 64 + cg];
        const float4 w3 = W4[(4 * kq + 3) * 64 + cg];
        #pragma unroll
        for (int r = 0; r < 4; ++r) {
            const float4 xv = ((const float4*)xs[4 * rg + r])[kq];
            acc[r].x = fmaf(xv.x, w0.x, fmaf(xv.y, w1.x, fmaf(xv.z, w2.x, fmaf(xv.w, w3.x, acc[r].x))));
            acc[r].y = fmaf(xv.x, w0.y, fmaf(xv.y, w1.y, fmaf(xv.z, w2.y, fmaf(xv.w, w3.y, acc[r].y))));
            acc[r].z = fmaf(xv.x, w0.z, fmaf(xv.y, w1.z, fmaf(xv.z, w2.z, fmaf(xv.w, w3.z, acc[r].z))));
            acc[r].w = fmaf(xv.x, w0.w, fmaf(xv.y, w1.w, fmaf(xv.z, w2.w, fmaf(xv.w, w3.w, acc[r].w))));
        }
    }

    if (!transposed) {
        #pragma unroll
        for (int r = 0; r < 4; ++r)
            ((float4*)(out + (m0 + 4 * rg + r) * HID))[cg] = acc[r];
    } else {
        const int b = m0 >= NTOK;
        const int n0 = m0 - b * NTOK;
        #pragma unroll
        for (int r = 0; r < 4; ++r) {
            const int row = n0 + 4 * rg + r;
            float* ob = BbT + b * (HID * NTOK);
            ob[(4 * cg + 0) * NTOK + row] = acc[r].x;
            ob[(4 * cg + 1) * NTOK + row] = acc[r].y;
            ob[(4 * cg + 2) * NTOK + row] = acc[r].z;
            ob[(4 * cg + 3) * NTOK + row] = acc[r].w;
        }
    }
}

// ---------------------------------------------------------------------------
// Stage B: physics bias over valid pairs (R4 form -- best measured, 47.4us).
//   One row per 320-thread block, sparse compaction, LDS as/wp, dense
//   NEG_INF prefill so biasg carries the adjacency mask for attn.
// ---------------------------------------------------------------------------
__global__ __launch_bounds__(320) void pga_bias(
    const float* __restrict__ A, const float* __restrict__ BbT,
    const float* __restrict__ Wp2, const float* __restrict__ bp2,
    const int* __restrict__ adj, float* __restrict__ biasg)
{
    __shared__ float as[HID];
    __shared__ float4 wp[HID];
    __shared__ short jlist[NTOK];
    __shared__ int ccnt[8];

    const int t = threadIdx.x;          // 0..319
    const int b = blockIdx.x >> 9;
    const int i = blockIdx.x & 511;
    const int w = t >> 6, lane = t & 63;
    const unsigned long long ltm = (1ull << lane) - 1ull;

    if (t < HID) {
        as[t] = A[(b * NTOK + i) * HID + t];
        wp[t] = ((const float4*)Wp2)[t];
    }

    // ---- dense NEG_INF prefill of row i in all 4 head planes ----
    {
        float* o0 = biasg + (((size_t)b * HEADS) * NTOK + i) * NTOK;
        #pragma unroll
        for (int hh = 0; hh < 4; ++hh) {
            float* oh = o0 + (size_t)hh * NTOK * NTOK;
            for (int jj = t; jj < NTOK; jj += 320) oh[jj] = NEG_INF;
        }
    }

    // ---- ordered ballot compaction of row i ----
    const int c0 = w, c1 = w + 5;
    bool m0 = adj[i * NTOK + c0 * 64 + lane] > 0;
    bool m1 = (c1 < 8) ? (adj[i * NTOK + c1 * 64 + lane] > 0) : false;
    const unsigned long long bm0 = __ballot(m0);
    const unsigned long long bm1 = __ballot(m1);
    if (lane == 0) {
        ccnt[c0] = __popcll(bm0);
        if (c1 < 8) ccnt[c1] = __popcll(bm1);
    }
    __syncthreads();

    int pref0 = 0, pref1 = 0, tot = 0;
    #pragma unroll
    for (int c = 0; c < 8; ++c) {
        if (c == c0) pref0 = tot;
        if (c == c1) pref1 = tot;
        tot += ccnt[c];
    }
    if (m0) jlist[pref0 + __popcll(bm0 & ltm)] = (short)(c0 * 64 + lane);
    if (c1 < 8 && m1) jlist[pref1 + __popcll(bm1 & ltm)] = (short)(c1 * 64 + lane);
    __syncthreads();

    const float* bb = BbT + b * (HID * NTOK);
    const float4 bp = *(const float4*)bp2;

    for (int idx = t; idx < tot; idx += 320) {
        const int j = jlist[idx];
        float ah0 = 0.f, ah1 = 0.f, ah2 = 0.f, ah3 = 0.f;
        #pragma unroll 8
        for (int d = 0; d < HID; ++d) {
            const float g = fast_gelu(as[d] + bb[d * NTOK + j]);
            const float4 wv = wp[d];
            ah0 = fmaf(g, wv.x, ah0); ah1 = fmaf(g, wv.y, ah1);
            ah2 = fmaf(g, wv.z, ah2); ah3 = fmaf(g, wv.w, ah3);
        }
        float* o = biasg + (((size_t)b * HEADS) * NTOK + i) * NTOK + j;
        o[0 * NTOK * NTOK] = ah0 + bp.x;
        o[1 * NTOK * NTOK] = ah1 + bp.y;
        o[2 * NTOK * NTOK] = ah2 + bp.z;
        o[3 * NTOK * NTOK] = ah3 + bp.w;
    }
}

// ---------------------------------------------------------------------------
// Stage C: MFMA attention with INTRA-BLOCK j-split + merge. grid = 256 =
//   (b, h, qt32): each block does 16 q-rows x ALL 512 j. Wave w owns j-tile
//   [w*128, w*128+128): wave-private K staging in Kt[w] (no barrier before
//   QK^T), V straight to registers (R2-verified layout), per-wave (m,l,O)
//   then ONE LDS merge -> writes NORMALIZED O. Partials/mlbuf eliminated.
// ---------------------------------------------------------------------------
#define KT_STRIDE 72
#define PL_STRIDE 136

__global__ __launch_bounds__(256) void pga_attn(
    const float* __restrict__ Q, const float* __restrict__ K,
    const float* __restrict__ V, const float* __restrict__ biasg,
    float* __restrict__ Og)
{
    __shared__ short Kt[4][128 * KT_STRIDE];
    __shared__ short Pl[4][16 * PL_STRIDE];
    __shared__ float Om[4][16][68];
    __shared__ float2 ml[4][16];

    const int blk = blockIdx.x;
    const int qt = blk & 31;
    const int h  = (blk >> 5) & 3;
    const int b  = blk >> 7;
    const int t = threadIdx.x;
    const int w = t >> 6;
    const int lane = t & 63;
    const int ln15 = lane & 15;
    const int quad = lane >> 4;

    const int i0 = qt * 16;          // 16 q-rows per block (all waves)
    const int j0 = w * 128;          // wave-private j-tile

    // ---- issue bias loads FIRST (consumed after QK^T) ----
    float bpre[8][4];
    {
        const float* bgb = biasg + ((size_t)(b * HEADS + h)) * NTOK * NTOK;
        #pragma unroll
        for (int nt = 0; nt < 8; ++nt) {
            const int j = j0 + nt * 16 + ln15;
            #pragma unroll
            for (int r = 0; r < 4; ++r)
                bpre[nt][r] = bgb[(size_t)(i0 + quad * 4 + r) * NTOK + j];
        }
    }

    // ---- Q A-fragments (scale folded), float4 loads ----
    bf16x8 aq0, aq1;
    {
        const float* qrow = Q + ((size_t)(b * NTOK) + i0 + ln15) * HID + h * HD;
        const float4 q0 = ((const float4*)qrow)[quad * 2];
        const float4 q1 = ((const float4*)qrow)[quad * 2 + 1];
        const float4 q2 = ((const float4*)qrow)[8 + quad * 2];
        const float4 q3 = ((const float4*)qrow)[8 + quad * 2 + 1];
        aq0[0] = f2bf(q0.x * 0.125f); aq0[1] = f2bf(q0.y * 0.125f);
        aq0[2] = f2bf(q0.z * 0.125f); aq0[3] = f2bf(q0.w * 0.125f);
        aq0[4] = f2bf(q1.x * 0.125f); aq0[5] = f2bf(q1.y * 0.125f);
        aq0[6] = f2bf(q1.z * 0.125f); aq0[7] = f2bf(q1.w * 0.125f);
        aq1[0] = f2bf(q2.x * 0.125f); aq1[1] = f2bf(q2.y * 0.125f);
        aq1[2] = f2bf(q2.z * 0.125f); aq1[3] = f2bf(q2.w * 0.125f);
        aq1[4] = f2bf(q3.x * 0.125f); aq1[5] = f2bf(q3.y * 0.125f);
        aq1[6] = f2bf(q3.z * 0.125f); aq1[7] = f2bf(q3.w * 0.125f);
    }

    // ---- V B-fragments straight to registers (R2-verified layout) ----
    bf16x8 vfrag[4][4];
    {
        const float* vbase = V + ((size_t)(b * NTOK) + j0 + quad * 8) * HID + h * HD + ln15;
        #pragma unroll
        for (int dt = 0; dt < 4; ++dt)
            #pragma unroll
            for (int kt = 0; kt < 4; ++kt)
                #pragma unroll
                for (int jj = 0; jj < 8; ++jj)
                    vfrag[dt][kt][jj] = f2bf(vbase[(size_t)(kt * 32 + jj) * HID + dt * 16]);
    }

    // ---- wave-private K staging (no block barrier needed) ----
    #pragma unroll 4
    for (int it = 0; it < 32; ++it) {
        const int flat = it * 64 + lane;
        const int jl = flat >> 4, dq = flat & 15;
        const float4 kv = ((const float4*)(K + ((size_t)(b * NTOK) + j0 + jl) * HID + h * HD))[dq];
        bf16x4 ks;
        ks[0] = f2bf(kv.x); ks[1] = f2bf(kv.y); ks[2] = f2bf(kv.z); ks[3] = f2bf(kv.w);
        *(bf16x4*)&Kt[w][jl * KT_STRIDE + dq * 4] = ks;
    }

    // ---- S = Q K^T ----
    f32x4 s[8];
    #pragma unroll
    for (int nt = 0; nt < 8; ++nt) {
        const int krow = nt * 16 + ln15;
        const bf16x8 bk0 = *(const bf16x8*)&Kt[w][krow * KT_STRIDE + quad * 8];
        const bf16x8 bk1 = *(const bf16x8*)&Kt[w][krow * KT_STRIDE + 32 + quad * 8];
        f32x4 acc = (f32x4){0.f, 0.f, 0.f, 0.f};
        acc = __builtin_amdgcn_mfma_f32_16x16x32_bf16(aq0, bk0, acc, 0, 0, 0);
        acc = __builtin_amdgcn_mfma_f32_16x16x32_bf16(aq1, bk1, acc, 0, 0, 0);
        s[nt] = acc;
    }

    // ---- add masked bias ----
    #pragma unroll
    for (int nt = 0; nt < 8; ++nt)
        #pragma unroll
        for (int r = 0; r < 4; ++r)
            s[nt][r] += bpre[nt][r];

    // ---- per-wave softmax stats over its 128-j tile ----
    float p[8][4], m_r[4], l_r[4];
    #pragma unroll
    for (int r = 0; r < 4; ++r) {
        float mx = s[0][r];
        #pragma unroll
        for (int nt = 1; nt < 8; ++nt) mx = fmaxf(mx, s[nt][r]);
        #pragma unroll
        for (int off = 1; off < 16; off <<= 1) mx = fmaxf(mx, __shfl_xor(mx, off, 64));
        float rs = 0.f;
        #pragma unroll
        for (int nt = 0; nt < 8; ++nt) { p[nt][r] = __expf(s[nt][r] - mx); rs += p[nt][r]; }
        #pragma unroll
        for (int off = 1; off < 16; off <<= 1) rs += __shfl_xor(rs, off, 64);
        m_r[r] = mx; l_r[r] = rs;
    }

    // ---- P -> per-wave LDS (C-layout scatter), read back as A-frags ----
    #pragma unroll
    for (int nt = 0; nt < 8; ++nt)
        #pragma unroll
        for (int r = 0; r < 4; ++r)
            Pl[w][(quad * 4 + r) * PL_STRIDE + nt * 16 + ln15] = f2bf(p[nt][r]);

    bf16x8 ap[4];
    #pragma unroll
    for (int kt = 0; kt < 4; ++kt)
        ap[kt] = *(const bf16x8*)&Pl[w][ln15 * PL_STRIDE + kt * 32 + quad * 8];

    // ---- O_w = P V (unnormalized), V in registers ----
    f32x4 o_acc[4];
    #pragma unroll
    for (int dt = 0; dt < 4; ++dt) o_acc[dt] = (f32x4){0.f, 0.f, 0.f, 0.f};
    #pragma unroll
    for (int dt = 0; dt < 4; ++dt)
        #pragma unroll
        for (int kt = 0; kt < 4; ++kt)
            o_acc[dt] = __builtin_amdgcn_mfma_f32_16x16x32_bf16(ap[kt], vfrag[dt][kt], o_acc[dt], 0, 0, 0);

    // ---- stash wave partials, then intra-block merge ----
    #pragma unroll
    for (int dt = 0; dt < 4; ++dt)
        #pragma unroll
        for (int r = 0; r < 4; ++r)
            Om[w][quad * 4 + r][dt * 16 + ln15] = o_acc[dt][r];
    if (ln15 == 0) {
        #pragma unroll
        for (int r = 0; r < 4; ++r)
            ml[w][quad * 4 + r] = make_float2(m_r[r], l_r[r]);
    }
    __syncthreads();

    {
        const int row = t >> 4;          // 0..15
        const int dbase = (t & 15) * 4;  // 0..60
        float M = ml[0][row].x;
        #pragma unroll
        for (int s4 = 1; s4 < 4; ++s4) M = fmaxf(M, ml[s4][row].x);
        float L = 0.f, sc[4];
        #pragma unroll
        for (int s4 = 0; s4 < 4; ++s4) {
            sc[s4] = __expf(ml[s4][row].x - M);
            L += ml[s4][row].y * sc[s4];
        }
        const float inv = 1.0f / L;
        float4 v4;
        v4.x = (Om[0][row][dbase + 0] * sc[0] + Om[1][row][dbase + 0] * sc[1] +
                Om[2][row][dbase + 0] * sc[2] + Om[3][row][dbase + 0] * sc[3]) * inv;
        v4.y = (Om[0][row][dbase + 1] * sc[0] + Om[1][row][dbase + 1] * sc[1] +
                Om[2][row][dbase + 1] * sc[2] + Om[3][row][dbase + 1] * sc[3]) * inv;
        v4.z = (Om[0][row][dbase + 2] * sc[0] + Om[1][row][dbase + 2] * sc[1] +
                Om[2][row][dbase + 2] * sc[2] + Om[3][row][dbase + 2] * sc[3]) * inv;
        v4.w = (Om[0][row][dbase + 3] * sc[0] + Om[1][row][dbase + 3] * sc[1] +
                Om[2][row][dbase + 3] * sc[2] + Om[3][row][dbase + 3] * sc[3]) * inv;
        *(float4*)(Og + ((size_t)(b * NTOK) + i0 + row) * HID + h * HD + dbase) = v4;
    }
}

// ---------------------------------------------------------------------------
// Stage D: pure GEMM out = O@Wo + bo (merge now lives in pga_attn).
// ---------------------------------------------------------------------------
__global__ __launch_bounds__(256) void pga_outproj(
    const float* __restrict__ O,
    const float* __restrict__ Wo, const float* __restrict__ bo,
    float* __restrict__ out)
{
    __shared__ float xs[4][HID];
    const int m0 = blockIdx.x * 4;
    const int t = threadIdx.x;

    #pragma unroll
    for (int r = 0; r < 4; ++r)
        xs[r][t] = O[(size_t)(m0 + r) * HID + t];
    __syncthreads();

    const int cg = t & 63;
    const int rg = t >> 6;            // each thread: 1 row x 4 cols
    float4 acc = ((const float4*)bo)[cg];

    const float4* W4 = (const float4*)Wo;
    const float4* xrow = (const float4*)xs[rg];
    #pragma unroll 2
    for (int kq = 0; kq < 64; ++kq) {
        const float4 w0 = W4[(4 * kq + 0) * 64 + cg];
        const float4 w1 = W4[(4 * kq + 1) * 64 + cg];
        const float4 w2 = W4[(4 * kq + 2) * 64 + cg];
        const float4 w3 = W4[(4 * kq + 3) * 64 + cg];
        const float4 xv = xrow[kq];
        acc.x = fmaf(xv.x, w0.x, fmaf(xv.y, w1.x, fmaf(xv.z, w2.x, fmaf(xv.w, w3.x, acc.x))));
        acc.y = fmaf(xv.x, w0.y, fmaf(xv.y, w1.y, fmaf(xv.z, w2.y, fmaf(xv.w, w3.y, acc.y))));
        acc.z = fmaf(xv.x, w0.z, fmaf(xv.y, w1.z, fmaf(xv.z, w2.z, fmaf(xv.w, w3.z, acc.z))));
        acc.w = fmaf(xv.x, w0.w, fmaf(xv.y, w1.w, fmaf(xv.z, w2.w, fmaf(xv.w, w3.w, acc.w))));
    }
    ((float4*)(out + (m0 + rg) * HID))[cg] = acc;
}

extern "C" void kernel_launch(void* const* d_in, const int* in_sizes, int n_in,
                              void* d_out, int out_size, void* d_ws, size_t ws_size,
                              hipStream_t stream) {
    const float* x   = (const float*)d_in[0];
    const int*   adj = (const int*)d_in[1];
    const float* Wq  = (const float*)d_in[2];
    const float* bq  = (const float*)d_in[3];
    const float* Wk  = (const float*)d_in[4];
    const float* bk  = (const float*)d_in[5];
    const float* Wv  = (const float*)d_in[6];
    const float* bv  = (const float*)d_in[7];
    const float* Wo  = (const float*)d_in[8];
    const float* bo  = (const float*)d_in[9];
    const float* Wp1 = (const float*)d_in[10];
    const float* bp1 = (const float*)d_in[11];
    const float* Wp2 = (const float*)d_in[12];
    const float* bp2 = (const float*)d_in[13];
    float* out = (float*)d_out;

    // ws layout (floats). A dies after pga_bias and is reused as the
    // normalized O buffer written by pga_attn (same-stream ordering).
    float* ws   = (float*)d_ws;
    float* Q    = ws;
    float* K    = ws + 262144;
    float* V    = ws + 2 * 262144;
    float* A    = ws + 3 * 262144;     // -> O (normalized attn output)
    float* BbT  = ws + 4 * 262144;
    float* bias = ws + 5 * 262144;     // 2097152 floats

    pga_proj5<<<dim3(64, 5), 256, 0, stream>>>(x, Wq, bq, Wk, bk, Wv, bv,
                                               Wp1, bp1, Q, K, V, A, BbT);
    pga_bias<<<1024, 320, 0, stream>>>(A, BbT, Wp2, bp2, adj, bias);
    pga_attn<<<256, 256, 0, stream>>>(Q, K, V, bias, A);
    pga_outproj<<<256, 256, 0, stream>>>(A, Wo, bo, out);
}